// Round 18
// baseline (106.668 us; speedup 1.0000x reference)
//
#include <hip/hip_runtime.h>
#include <math.h>

#define H       2880
#define H4      720
#define NTOK    16384
#define NEXP    128
#define NCHUNK  90      // K-chunks of 32 fp32
#define NSTEP   180
#define KSW     4       // intra-block K-split (one wave per slice)
#define GAP_EPS 1e-3f   // approx-ranking trust margin (err rms ~7e-6)

typedef __attribute__((ext_vector_type(8)))  short bf16x8;
typedef __attribute__((ext_vector_type(16))) float f32x16;

union FragU { unsigned int u[4]; bf16x8 v; };

// hi = top 16 bits of fp32 (bf16 truncation); lo = bf16(x - hi).
__device__ inline bf16x8 pack_hi2(float4 a, float4 b) {
    const float f[8] = {a.x,a.y,a.z,a.w,b.x,b.y,b.z,b.w};
    FragU r;
#pragma unroll
    for (int j = 0; j < 4; ++j) {
        unsigned u0 = __float_as_uint(f[2*j]);
        unsigned u1 = __float_as_uint(f[2*j+1]);
        r.u[j] = (u1 & 0xFFFF0000u) | (u0 >> 16);
    }
    return r.v;
}
__device__ inline bf16x8 pack_lo2(float4 a, float4 b) {
    const float f[8] = {a.x,a.y,a.z,a.w,b.x,b.y,b.z,b.w};
    FragU r;
#pragma unroll
    for (int j = 0; j < 4; ++j) {
        float x0 = f[2*j],   h0 = __uint_as_float(__float_as_uint(x0) & 0xFFFF0000u);
        float x1 = f[2*j+1], h1 = __uint_as_float(__float_as_uint(x1) & 0xFFFF0000u);
        unsigned l0 = __float_as_uint(x0 - h0);
        unsigned l1 = __float_as_uint(x1 - h1);
        r.u[j] = (l1 & 0xFFFF0000u) | (l0 >> 16);
    }
    return r.v;
}

// ---------------- Kernel 0: w -> bf16 hi/lo planes in MFMA-FRAGMENT order ----------------
__global__ __launch_bounds__(256) void wconv(
    const float* __restrict__ w, short* __restrict__ whiF, short* __restrict__ wloF)
{
    const int gid = blockIdx.x * 256 + threadIdx.x;   // 180*4*64 = 46080
    const int l   = gid & 63;
    const int nt  = (gid >> 6) & 3;
    const int s   = gid >> 8;
    const int e   = nt * 32 + (l & 31);
    const int k0  = s * 16 + (l >> 5) * 8;
    const float4* wp = (const float4*)(w + (size_t)e * H + k0);
    const float4 a = wp[0], b = wp[1];
    *(bf16x8*)(whiF + (size_t)gid * 8) = pack_hi2(a, b);
    *(bf16x8*)(wloF + (size_t)gid * 8) = pack_lo2(a, b);
}

// ---------------- Kernel 1: MFMA GEMM, intra-block split-K, fused reduce+topk tail ----------
// 512 blocks x 4 waves. Wave wv runs the R9-proven pipeline VERBATIM on K-slice wv
// (wave-private LDS, per-wave counted vmcnt, no barriers in the loop). x staging uses
// NT cache hint (aux=2) so the single-use x stream doesn't evict B planes from L2.
// Tail: ALL waves dump acc to 64 KB LDS exchange -> 8 half-wave groups combine (fixed
// order) + bias -> write FINAL logits -> width-32 butterfly top-8 + gap gate + softmax.
// All tail indexing static (rule-20 safe); acc dead before top-k.
__global__ __launch_bounds__(256, 2) void router_gemm_fused(
    const float* __restrict__ x,
    const short* __restrict__ whiF,
    const short* __restrict__ wloF,
    const float* __restrict__ bias,
    float* __restrict__ logits,
    int* __restrict__ cand,             // [NTOK][8]; cand[t*8] bit30 = needs exact fixup
    float* __restrict__ vals,
    float* __restrict__ inds)
{
    __shared__ float xs[4][4096];       // 64 KB: staging (3x4KB/wave) + acc-exchange reuse

    const int tid  = threadIdx.x;
    const int lane = tid & 63;
    const int wv   = tid >> 6;
    const int bm   = blockIdx.x;        // 0..511
    const int t0   = bm * 32;

    // even-length K slices per wave: 24/22/22/22, all c0 even
    const int base2 = (NCHUNK / KSW) & ~1;
    const int pairs = (NCHUNK - base2 * KSW) >> 1;
    const int c0 = wv * base2 + 2 * (wv < pairs ? wv : pairs);
    const int c1 = c0 + base2 + (wv < pairs ? 2 : 0);

    // stage source: lane l covers rows (l>>3)+8i, pre-swizzled col (l&7)^(l>>3)
    const float4* gs = (const float4*)x + (size_t)(t0 + (lane >> 3)) * H4 + ((lane & 7) ^ (lane >> 3));
    const unsigned xsb = (unsigned)(uintptr_t)&xs[wv][0];
    const int r31 = lane & 31, lx7 = lane & 7, kh2 = (lane >> 5) * 2;

    f32x16 acc[4];
#pragma unroll
    for (int nt = 0; nt < 4; ++nt)
#pragma unroll
        for (int r = 0; r < 16; ++r) acc[nt][r] = 0.0f;

    bf16x8 bA[16], bB[16];              // static banks: even / odd chunks

// aux=2 -> NT (non-temporal) cache policy: x is single-use, keep B resident in L2
#define GL(SRC, DST) __builtin_amdgcn_global_load_lds(                                   \
        (const __attribute__((address_space(1))) void*)(SRC),                            \
        (__attribute__((address_space(3))) void*)(DST), 16, 0, 2)

#define STAGE(SB, CC) {                                                                  \
    const float4* g_ = gs + (size_t)(CC) * 8;                                            \
    GL(g_,                  &xs[wv][(SB) * 1024 + 0]);                                   \
    GL(g_ + (size_t) 8*H4,  &xs[wv][(SB) * 1024 + 256]);                                 \
    GL(g_ + (size_t)16*H4,  &xs[wv][(SB) * 1024 + 512]);                                 \
    GL(g_ + (size_t)24*H4,  &xs[wv][(SB) * 1024 + 768]); }

#define BLOAD_ST(DST, CC, ST) {                                                          \
    _Pragma("unroll")                                                                    \
    for (int nt = 0; nt < 4; ++nt) {                                                     \
        const size_t o_ = ((size_t)(((CC)*2 + (ST))*4 + nt)*64 + lane) * 8;              \
        DST[(ST)*8 + nt*2]     = *(const bf16x8*)(whiF + o_);                            \
        DST[(ST)*8 + nt*2 + 1] = *(const bf16x8*)(wloF + o_); } }

#define MFMA_HALF(BANK, ST, AH, AL) {                                                    \
    _Pragma("unroll")                                                                    \
    for (int nt = 0; nt < 4; ++nt) {                                                     \
        acc[nt] = __builtin_amdgcn_mfma_f32_32x32x16_bf16(AH, BANK[(ST)*8 + nt*2],     acc[nt], 0,0,0); \
        acc[nt] = __builtin_amdgcn_mfma_f32_32x32x16_bf16(AL, BANK[(ST)*8 + nt*2],     acc[nt], 0,0,0); \
        acc[nt] = __builtin_amdgcn_mfma_f32_32x32x16_bf16(AH, BANK[(ST)*8 + nt*2 + 1], acc[nt], 0,0,0); } }

#define DSREAD_PACK(BUF, AH0, AL0, AH1, AL1) {                                           \
    const unsigned ab  = xsb + (unsigned)(BUF) * 4096u + (unsigned)r31 * 128u;           \
    const unsigned a00 = ab + 16u * (unsigned)((kh2    ) ^ lx7);                         \
    const unsigned a01 = ab + 16u * (unsigned)((kh2 + 1) ^ lx7);                         \
    const unsigned a10 = ab + 16u * (unsigned)((kh2 + 4) ^ lx7);                         \
    const unsigned a11 = ab + 16u * (unsigned)((kh2 + 5) ^ lx7);                         \
    float4 q0, q1, q2, q3;                                                               \
    asm volatile("ds_read_b128 %0, %1" : "=v"(q0) : "v"(a00) : "memory");                \
    asm volatile("ds_read_b128 %0, %1" : "=v"(q1) : "v"(a01) : "memory");                \
    asm volatile("ds_read_b128 %0, %1" : "=v"(q2) : "v"(a10) : "memory");                \
    asm volatile("ds_read_b128 %0, %1" : "=v"(q3) : "v"(a11) : "memory");                \
    asm volatile("s_waitcnt lgkmcnt(0)" ::: "memory");                                   \
    __builtin_amdgcn_sched_barrier(0);                                                   \
    AH0 = pack_hi2(q0, q1); AL0 = pack_lo2(q0, q1);                                      \
    AH1 = pack_hi2(q2, q3); AL1 = pack_lo2(q2, q3); }

    // ---- R9-proven pipeline, verbatim (vmcnt is per-wave state; counts unchanged) ----
    STAGE(0, c0);
    STAGE(1, c0 + 1);
    BLOAD_ST(bA, c0, 0);     BLOAD_ST(bA, c0, 1);
    BLOAD_ST(bB, c0 + 1, 0); BLOAD_ST(bB, c0 + 1, 1);

    int rb = 0;
    bf16x8 ah0, al0, ah1, al1;
    for (int c = c0; c < c1 - 2; c += 2) {
        const int sb  = (rb + 2 >= 3) ? rb - 1 : rb + 2;
        const int rb1 = (rb + 1 >= 3) ? 0 : rb + 1;
        STAGE(sb, c + 2);
        asm volatile("s_waitcnt vmcnt(40)" ::: "memory");
        DSREAD_PACK(rb, ah0, al0, ah1, al1);
        MFMA_HALF(bA, 0, ah0, al0);
        BLOAD_ST(bA, c + 2, 0);
        MFMA_HALF(bA, 1, ah1, al1);
        BLOAD_ST(bA, c + 2, 1);
        STAGE(rb, c + 3);
        asm volatile("s_waitcnt vmcnt(40)" ::: "memory");
        DSREAD_PACK(rb1, ah0, al0, ah1, al1);
        MFMA_HALF(bB, 0, ah0, al0);
        BLOAD_ST(bB, c + 3, 0);
        MFMA_HALF(bB, 1, ah1, al1);
        BLOAD_ST(bB, c + 3, 1);
        rb = (rb >= 1) ? rb - 1 : 2;
    }
    {
        const int rb1 = (rb + 1 >= 3) ? 0 : rb + 1;
        asm volatile("s_waitcnt vmcnt(36)" ::: "memory");
        DSREAD_PACK(rb, ah0, al0, ah1, al1);
        MFMA_HALF(bA, 0, ah0, al0);
        MFMA_HALF(bA, 1, ah1, al1);
        asm volatile("s_waitcnt vmcnt(16)" ::: "memory");
        DSREAD_PACK(rb1, ah0, al0, ah1, al1);
        MFMA_HALF(bB, 0, ah0, al0);
        MFMA_HALF(bB, 1, ah1, al1);
    }

    // ---- fused tail: ALL waves dump acc into the (now dead) staging LDS ----
    __syncthreads();                    // all waves done with staging LDS
    float* exch = &xs[0][0];            // 4 regions x 4096 floats
    {
        const int eb = wv * 4096;
#pragma unroll
        for (int nt = 0; nt < 4; ++nt)
#pragma unroll
            for (int r = 0; r < 16; ++r)
                exch[eb + (nt * 16 + r) * 64 + lane] = acc[nt][r];  // lane-consecutive
    }
    __syncthreads();

    // 8 half-wave groups (wv,h): each combines+tops 4 tokens. All static indexing.
    const int h = lane >> 5;
    const int c_ = lane & 31;
    const int g = wv * 2 + h;

    for (int i = 0; i < 4; ++i) {
        const int tr  = g * 4 + i;      // token row in tile, 0..31
        const int tok = t0 + tr;
        const int hh  = (tr >> 2) & 1;
        const int rr  = (tr & 3) + ((tr >> 3) << 2);

        float v[4];
#pragma unroll
        for (int nt = 0; nt < 4; ++nt) {
            const int sl = (nt * 16 + rr) * 64 + (hh << 5) + c_;
            // fixed order: ((w0 + w1) + w2) + w3 + bias  (bit-identical to R17)
            const float s = ((exch[sl] + exch[4096 + sl]) + exch[8192 + sl]) + exch[12288 + sl]
                            + bias[nt * 32 + c_];
            v[nt] = s;
            logits[(size_t)tok * NEXP + nt * 32 + c_] = s;
        }

        float vv[8]; int out8[8];
#pragma unroll
        for (int r = 0; r < 8; ++r) {
            float lv = v[0]; int lj = 0;
#pragma unroll
            for (int j = 1; j < 4; ++j) if (v[j] > lv) { lv = v[j]; lj = j; }
            int le = lj * 32 + c_;      // strict > kept lowest j = lowest expert index
#pragma unroll
            for (int m = 1; m < 32; m <<= 1) {   // width-32: halves independent
                const float ov = __shfl_xor(lv, m, 32);
                const int   oe = __shfl_xor(le, m, 32);
                if (ov > lv || (ov == lv && oe < le)) { lv = ov; le = oe; }
            }
            vv[r] = lv; out8[r] = le;            // identical in all 32 lanes of the group
            // retire winner slot -- STATIC indices only (rule-20 safe)
            const bool mine = (le & 31) == c_;
            const int  sel  = le >> 5;
            v[0] = (mine && sel == 0) ? -3.4e38f : v[0];
            v[1] = (mine && sel == 1) ? -3.4e38f : v[1];
            v[2] = (mine && sel == 2) ? -3.4e38f : v[2];
            v[3] = (mine && sel == 3) ? -3.4e38f : v[3];
        }

        float ming = vv[0] - vv[1];
        ming = fminf(ming, vv[1] - vv[2]);
        ming = fminf(ming, vv[2] - vv[3]);
        ming = fminf(ming, vv[3] - vv[4]);
        const bool slow = (ming < GAP_EPS);

        if (c_ == 0) {
            int4 o0 = {out8[0] | (slow ? (1 << 30) : 0), out8[1], out8[2], out8[3]};
            int4 o1 = {out8[4], out8[5], out8[6], out8[7]};
            *(int4*)(cand + (size_t)tok * 8)     = o0;
            *(int4*)(cand + (size_t)tok * 8 + 4) = o1;
            if (!slow) {
                const float e1 = expf(vv[1] - vv[0]);
                const float e2 = expf(vv[2] - vv[0]);
                const float e3 = expf(vv[3] - vv[0]);
                const float sm = 1.0f + e1 + e2 + e3;
                float4 ov = {1.0f / sm, e1 / sm, e2 / sm, e3 / sm};
                float4 oi = {(float)out8[0], (float)out8[1], (float)out8[2], (float)out8[3]};
                *(float4*)(&vals[(size_t)tok * 4]) = ov;
                *(float4*)(&inds[(size_t)tok * 4]) = oi;
            }
        }
    }
}

// ---------------- Kernel 2: exact fp64 recompute, only for flagged tokens --------------------
__global__ __launch_bounds__(256) void fixup_topk(
    const float* __restrict__ x,
    const float* __restrict__ w,
    const float* __restrict__ bias,
    const int* __restrict__ cand,
    float* __restrict__ vals,
    float* __restrict__ inds)
{
    const int lane = threadIdx.x & 63;
    const int wv   = threadIdx.x >> 6;
    const int tok  = blockIdx.x * 4 + wv;

    const int head = cand[(size_t)tok * 8];
    if (!(head & (1 << 30))) return;    // fast-path token, already written

    const int c    = lane >> 3;
    const int s    = lane & 7;
    const int cidx = cand[(size_t)tok * 8 + c] & 0x3fffffff;

    const float4* xr = (const float4*)x + (size_t)tok  * H4;
    const float4* wr = (const float4*)w + (size_t)cidx * H4;

    double acc = 0.0;
    for (int j = 0; j < 90; ++j) {
        const float4 a = xr[s + 8 * j];
        const float4 b = wr[s + 8 * j];
        acc = fma((double)a.x, (double)b.x, acc);
        acc = fma((double)a.y, (double)b.y, acc);
        acc = fma((double)a.z, (double)b.z, acc);
        acc = fma((double)a.w, (double)b.w, acc);
    }
    acc += __shfl_xor(acc, 1);
    acc += __shfl_xor(acc, 2);
    acc += __shfl_xor(acc, 4);
    const double exact = acc + (double)bias[cidx];

    double bv[8]; int bidx[8];
#pragma unroll
    for (int g = 0; g < 8; ++g) { bv[g] = __shfl(exact, g * 8); bidx[g] = __shfl(cidx, g * 8); }

    float fv[4]; int fi[4];
#pragma unroll
    for (int k = 0; k < 4; ++k) {
        double best = -1.0e300; int bi = 1 << 30; int bg = -1;
#pragma unroll
        for (int g = 0; g < 8; ++g) {
            if (bv[g] > best || (bv[g] == best && bidx[g] < bi)) { best = bv[g]; bi = bidx[g]; bg = g; }
        }
#pragma unroll
        for (int g = 0; g < 8; ++g) if (g == bg) bv[g] = -1.0e300;
        fv[k] = (float)best; fi[k] = bi;
    }

    if (lane == 0) {
        const float e1 = expf(fv[1] - fv[0]);
        const float e2 = expf(fv[2] - fv[0]);
        const float e3 = expf(fv[3] - fv[0]);
        const float sm = 1.0f + e1 + e2 + e3;
        float4 ov = {1.0f / sm, e1 / sm, e2 / sm, e3 / sm};
        float4 oi = {(float)fi[0], (float)fi[1], (float)fi[2], (float)fi[3]};
        *(float4*)(&vals[(size_t)tok * 4]) = ov;
        *(float4*)(&inds[(size_t)tok * 4]) = oi;
    }
}

extern "C" void kernel_launch(void* const* d_in, const int* in_sizes, int n_in,
                              void* d_out, int out_size, void* d_ws, size_t ws_size,
                              hipStream_t stream) {
    const float* x    = (const float*)d_in[0];
    const float* w    = (const float*)d_in[1];
    const float* bias = (const float*)d_in[2];

    float* out    = (float*)d_out;
    float* vals   = out;                 // 16384*4
    float* inds   = out + NTOK * 4;      // 16384*4
    float* logits = out + NTOK * 8;      // 16384*128

    // ws layout: whiF | wloF | cand  (~2 MB; no split-K partials)
    short* whiF = (short*)d_ws;
    short* wloF = whiF + (size_t)NEXP * H;
    int*   cand = (int*)(wloF + (size_t)NEXP * H);

    wconv<<<NSTEP, 256, 0, stream>>>(w, whiF, wloF);
    router_gemm_fused<<<NTOK / 32, 256, 0, stream>>>(
        x, whiF, wloF, bias, logits, cand, vals, inds);
    fixup_topk<<<NTOK / 4, 256, 0, stream>>>(x, w, bias, cand, vals, inds);
}

// Round 19
// 87.191 us; speedup vs baseline: 1.2234x; 1.2234x over previous
//
#include <hip/hip_runtime.h>
#include <math.h>

#define H       2880
#define H4      720
#define NTOK    16384
#define NEXP    128
#define NCHUNK  90      // K-chunks of 32 fp32
#define NSTEP   180
#define KSW     4       // intra-block K-split (one wave per slice)
#define GAP_EPS 1e-3f   // approx-ranking trust margin (err rms ~7e-6)

typedef __attribute__((ext_vector_type(8)))  short bf16x8;
typedef __attribute__((ext_vector_type(16))) float f32x16;

union FragU { unsigned int u[4]; bf16x8 v; };

// hi = top 16 bits of fp32 (bf16 truncation); lo = bf16(x - hi).
__device__ inline bf16x8 pack_hi2(float4 a, float4 b) {
    const float f[8] = {a.x,a.y,a.z,a.w,b.x,b.y,b.z,b.w};
    FragU r;
#pragma unroll
    for (int j = 0; j < 4; ++j) {
        unsigned u0 = __float_as_uint(f[2*j]);
        unsigned u1 = __float_as_uint(f[2*j+1]);
        r.u[j] = (u1 & 0xFFFF0000u) | (u0 >> 16);
    }
    return r.v;
}
__device__ inline bf16x8 pack_lo2(float4 a, float4 b) {
    const float f[8] = {a.x,a.y,a.z,a.w,b.x,b.y,b.z,b.w};
    FragU r;
#pragma unroll
    for (int j = 0; j < 4; ++j) {
        float x0 = f[2*j],   h0 = __uint_as_float(__float_as_uint(x0) & 0xFFFF0000u);
        float x1 = f[2*j+1], h1 = __uint_as_float(__float_as_uint(x1) & 0xFFFF0000u);
        unsigned l0 = __float_as_uint(x0 - h0);
        unsigned l1 = __float_as_uint(x1 - h1);
        r.u[j] = (l1 & 0xFFFF0000u) | (l0 >> 16);
    }
    return r.v;
}

// ---------------- Kernel 0: w -> bf16 hi/lo planes in MFMA-FRAGMENT order ----------------
__global__ __launch_bounds__(256) void wconv(
    const float* __restrict__ w, short* __restrict__ whiF, short* __restrict__ wloF)
{
    const int gid = blockIdx.x * 256 + threadIdx.x;   // 180*4*64 = 46080
    const int l   = gid & 63;
    const int nt  = (gid >> 6) & 3;
    const int s   = gid >> 8;
    const int e   = nt * 32 + (l & 31);
    const int k0  = s * 16 + (l >> 5) * 8;
    const float4* wp = (const float4*)(w + (size_t)e * H + k0);
    const float4 a = wp[0], b = wp[1];
    *(bf16x8*)(whiF + (size_t)gid * 8) = pack_hi2(a, b);
    *(bf16x8*)(wloF + (size_t)gid * 8) = pack_lo2(a, b);
}

// ---------------- Kernel 1: MFMA GEMM, intra-block split-K, fused reduce+topk tail ----------
// 512 blocks x 4 waves. Wave wv runs the R9-proven pipeline VERBATIM on K-slice wv
// (wave-private LDS, per-wave counted vmcnt, no barriers in the loop). Default cache
// policy on staging (R18's NT hint cost ~25 us: it forfeited x's ~40% L3 hit rate).
// Tail: ALL waves dump acc to 64 KB LDS exchange -> 8 half-wave groups combine (fixed
// order) + bias -> write FINAL logits -> width-32 butterfly top-8 + gap gate + softmax.
// All tail indexing static (rule-20 safe); acc dead before top-k.
__global__ __launch_bounds__(256, 2) void router_gemm_fused(
    const float* __restrict__ x,
    const short* __restrict__ whiF,
    const short* __restrict__ wloF,
    const float* __restrict__ bias,
    float* __restrict__ logits,
    int* __restrict__ cand,             // [NTOK][8]; cand[t*8] bit30 = needs exact fixup
    float* __restrict__ vals,
    float* __restrict__ inds)
{
    __shared__ float xs[4][4096];       // 64 KB: staging (3x4KB/wave) + acc-exchange reuse

    const int tid  = threadIdx.x;
    const int lane = tid & 63;
    const int wv   = tid >> 6;
    const int bm   = blockIdx.x;        // 0..511
    const int t0   = bm * 32;

    // even-length K slices per wave: 24/22/22/22, all c0 even
    const int base2 = (NCHUNK / KSW) & ~1;
    const int pairs = (NCHUNK - base2 * KSW) >> 1;
    const int c0 = wv * base2 + 2 * (wv < pairs ? wv : pairs);
    const int c1 = c0 + base2 + (wv < pairs ? 2 : 0);

    // stage source: lane l covers rows (l>>3)+8i, pre-swizzled col (l&7)^(l>>3)
    const float4* gs = (const float4*)x + (size_t)(t0 + (lane >> 3)) * H4 + ((lane & 7) ^ (lane >> 3));
    const unsigned xsb = (unsigned)(uintptr_t)&xs[wv][0];
    const int r31 = lane & 31, lx7 = lane & 7, kh2 = (lane >> 5) * 2;

    f32x16 acc[4];
#pragma unroll
    for (int nt = 0; nt < 4; ++nt)
#pragma unroll
        for (int r = 0; r < 16; ++r) acc[nt][r] = 0.0f;

    bf16x8 bA[16], bB[16];              // static banks: even / odd chunks

#define GL(SRC, DST) __builtin_amdgcn_global_load_lds(                                   \
        (const __attribute__((address_space(1))) void*)(SRC),                            \
        (__attribute__((address_space(3))) void*)(DST), 16, 0, 0)

#define STAGE(SB, CC) {                                                                  \
    const float4* g_ = gs + (size_t)(CC) * 8;                                            \
    GL(g_,                  &xs[wv][(SB) * 1024 + 0]);                                   \
    GL(g_ + (size_t) 8*H4,  &xs[wv][(SB) * 1024 + 256]);                                 \
    GL(g_ + (size_t)16*H4,  &xs[wv][(SB) * 1024 + 512]);                                 \
    GL(g_ + (size_t)24*H4,  &xs[wv][(SB) * 1024 + 768]); }

#define BLOAD_ST(DST, CC, ST) {                                                          \
    _Pragma("unroll")                                                                    \
    for (int nt = 0; nt < 4; ++nt) {                                                     \
        const size_t o_ = ((size_t)(((CC)*2 + (ST))*4 + nt)*64 + lane) * 8;              \
        DST[(ST)*8 + nt*2]     = *(const bf16x8*)(whiF + o_);                            \
        DST[(ST)*8 + nt*2 + 1] = *(const bf16x8*)(wloF + o_); } }

#define MFMA_HALF(BANK, ST, AH, AL) {                                                    \
    _Pragma("unroll")                                                                    \
    for (int nt = 0; nt < 4; ++nt) {                                                     \
        acc[nt] = __builtin_amdgcn_mfma_f32_32x32x16_bf16(AH, BANK[(ST)*8 + nt*2],     acc[nt], 0,0,0); \
        acc[nt] = __builtin_amdgcn_mfma_f32_32x32x16_bf16(AL, BANK[(ST)*8 + nt*2],     acc[nt], 0,0,0); \
        acc[nt] = __builtin_amdgcn_mfma_f32_32x32x16_bf16(AH, BANK[(ST)*8 + nt*2 + 1], acc[nt], 0,0,0); } }

#define DSREAD_PACK(BUF, AH0, AL0, AH1, AL1) {                                           \
    const unsigned ab  = xsb + (unsigned)(BUF) * 4096u + (unsigned)r31 * 128u;           \
    const unsigned a00 = ab + 16u * (unsigned)((kh2    ) ^ lx7);                         \
    const unsigned a01 = ab + 16u * (unsigned)((kh2 + 1) ^ lx7);                         \
    const unsigned a10 = ab + 16u * (unsigned)((kh2 + 4) ^ lx7);                         \
    const unsigned a11 = ab + 16u * (unsigned)((kh2 + 5) ^ lx7);                         \
    float4 q0, q1, q2, q3;                                                               \
    asm volatile("ds_read_b128 %0, %1" : "=v"(q0) : "v"(a00) : "memory");                \
    asm volatile("ds_read_b128 %0, %1" : "=v"(q1) : "v"(a01) : "memory");                \
    asm volatile("ds_read_b128 %0, %1" : "=v"(q2) : "v"(a10) : "memory");                \
    asm volatile("ds_read_b128 %0, %1" : "=v"(q3) : "v"(a11) : "memory");                \
    asm volatile("s_waitcnt lgkmcnt(0)" ::: "memory");                                   \
    __builtin_amdgcn_sched_barrier(0);                                                   \
    AH0 = pack_hi2(q0, q1); AL0 = pack_lo2(q0, q1);                                      \
    AH1 = pack_hi2(q2, q3); AL1 = pack_lo2(q2, q3); }

    // ---- R9-proven pipeline, verbatim (vmcnt is per-wave state; counts unchanged) ----
    STAGE(0, c0);
    STAGE(1, c0 + 1);
    BLOAD_ST(bA, c0, 0);     BLOAD_ST(bA, c0, 1);
    BLOAD_ST(bB, c0 + 1, 0); BLOAD_ST(bB, c0 + 1, 1);

    int rb = 0;
    bf16x8 ah0, al0, ah1, al1;
    for (int c = c0; c < c1 - 2; c += 2) {
        const int sb  = (rb + 2 >= 3) ? rb - 1 : rb + 2;
        const int rb1 = (rb + 1 >= 3) ? 0 : rb + 1;
        STAGE(sb, c + 2);
        asm volatile("s_waitcnt vmcnt(40)" ::: "memory");
        DSREAD_PACK(rb, ah0, al0, ah1, al1);
        MFMA_HALF(bA, 0, ah0, al0);
        BLOAD_ST(bA, c + 2, 0);
        MFMA_HALF(bA, 1, ah1, al1);
        BLOAD_ST(bA, c + 2, 1);
        STAGE(rb, c + 3);
        asm volatile("s_waitcnt vmcnt(40)" ::: "memory");
        DSREAD_PACK(rb1, ah0, al0, ah1, al1);
        MFMA_HALF(bB, 0, ah0, al0);
        BLOAD_ST(bB, c + 3, 0);
        MFMA_HALF(bB, 1, ah1, al1);
        BLOAD_ST(bB, c + 3, 1);
        rb = (rb >= 1) ? rb - 1 : 2;
    }
    {
        const int rb1 = (rb + 1 >= 3) ? 0 : rb + 1;
        asm volatile("s_waitcnt vmcnt(36)" ::: "memory");
        DSREAD_PACK(rb, ah0, al0, ah1, al1);
        MFMA_HALF(bA, 0, ah0, al0);
        MFMA_HALF(bA, 1, ah1, al1);
        asm volatile("s_waitcnt vmcnt(16)" ::: "memory");
        DSREAD_PACK(rb1, ah0, al0, ah1, al1);
        MFMA_HALF(bB, 0, ah0, al0);
        MFMA_HALF(bB, 1, ah1, al1);
    }

    // ---- fused tail: ALL waves dump acc into the (now dead) staging LDS ----
    __syncthreads();                    // all waves done with staging LDS
    float* exch = &xs[0][0];            // 4 regions x 4096 floats
    {
        const int eb = wv * 4096;
#pragma unroll
        for (int nt = 0; nt < 4; ++nt)
#pragma unroll
            for (int r = 0; r < 16; ++r)
                exch[eb + (nt * 16 + r) * 64 + lane] = acc[nt][r];  // lane-consecutive
    }
    __syncthreads();

    // 8 half-wave groups (wv,h): each combines+tops 4 tokens. All static indexing.
    const int h = lane >> 5;
    const int c_ = lane & 31;
    const int g = wv * 2 + h;

    for (int i = 0; i < 4; ++i) {
        const int tr  = g * 4 + i;      // token row in tile, 0..31
        const int tok = t0 + tr;
        const int hh  = (tr >> 2) & 1;
        const int rr  = (tr & 3) + ((tr >> 3) << 2);

        float v[4];
#pragma unroll
        for (int nt = 0; nt < 4; ++nt) {
            const int sl = (nt * 16 + rr) * 64 + (hh << 5) + c_;
            // fixed order: ((w0 + w1) + w2) + w3 + bias  (bit-identical to R17)
            const float s = ((exch[sl] + exch[4096 + sl]) + exch[8192 + sl]) + exch[12288 + sl]
                            + bias[nt * 32 + c_];
            v[nt] = s;
            logits[(size_t)tok * NEXP + nt * 32 + c_] = s;
        }

        float vv[8]; int out8[8];
#pragma unroll
        for (int r = 0; r < 8; ++r) {
            float lv = v[0]; int lj = 0;
#pragma unroll
            for (int j = 1; j < 4; ++j) if (v[j] > lv) { lv = v[j]; lj = j; }
            int le = lj * 32 + c_;      // strict > kept lowest j = lowest expert index
#pragma unroll
            for (int m = 1; m < 32; m <<= 1) {   // width-32: halves independent
                const float ov = __shfl_xor(lv, m, 32);
                const int   oe = __shfl_xor(le, m, 32);
                if (ov > lv || (ov == lv && oe < le)) { lv = ov; le = oe; }
            }
            vv[r] = lv; out8[r] = le;            // identical in all 32 lanes of the group
            // retire winner slot -- STATIC indices only (rule-20 safe)
            const bool mine = (le & 31) == c_;
            const int  sel  = le >> 5;
            v[0] = (mine && sel == 0) ? -3.4e38f : v[0];
            v[1] = (mine && sel == 1) ? -3.4e38f : v[1];
            v[2] = (mine && sel == 2) ? -3.4e38f : v[2];
            v[3] = (mine && sel == 3) ? -3.4e38f : v[3];
        }

        float ming = vv[0] - vv[1];
        ming = fminf(ming, vv[1] - vv[2]);
        ming = fminf(ming, vv[2] - vv[3]);
        ming = fminf(ming, vv[3] - vv[4]);
        const bool slow = (ming < GAP_EPS);

        if (c_ == 0) {
            int4 o0 = {out8[0] | (slow ? (1 << 30) : 0), out8[1], out8[2], out8[3]};
            int4 o1 = {out8[4], out8[5], out8[6], out8[7]};
            *(int4*)(cand + (size_t)tok * 8)     = o0;
            *(int4*)(cand + (size_t)tok * 8 + 4) = o1;
            if (!slow) {
                const float e1 = expf(vv[1] - vv[0]);
                const float e2 = expf(vv[2] - vv[0]);
                const float e3 = expf(vv[3] - vv[0]);
                const float sm = 1.0f + e1 + e2 + e3;
                float4 ov = {1.0f / sm, e1 / sm, e2 / sm, e3 / sm};
                float4 oi = {(float)out8[0], (float)out8[1], (float)out8[2], (float)out8[3]};
                *(float4*)(&vals[(size_t)tok * 4]) = ov;
                *(float4*)(&inds[(size_t)tok * 4]) = oi;
            }
        }
    }
}

// ---------------- Kernel 2: exact fp64 recompute, only for flagged tokens --------------------
__global__ __launch_bounds__(256) void fixup_topk(
    const float* __restrict__ x,
    const float* __restrict__ w,
    const float* __restrict__ bias,
    const int* __restrict__ cand,
    float* __restrict__ vals,
    float* __restrict__ inds)
{
    const int lane = threadIdx.x & 63;
    const int wv   = threadIdx.x >> 6;
    const int tok  = blockIdx.x * 4 + wv;

    const int head = cand[(size_t)tok * 8];
    if (!(head & (1 << 30))) return;    // fast-path token, already written

    const int c    = lane >> 3;
    const int s    = lane & 7;
    const int cidx = cand[(size_t)tok * 8 + c] & 0x3fffffff;

    const float4* xr = (const float4*)x + (size_t)tok  * H4;
    const float4* wr = (const float4*)w + (size_t)cidx * H4;

    double acc = 0.0;
    for (int j = 0; j < 90; ++j) {
        const float4 a = xr[s + 8 * j];
        const float4 b = wr[s + 8 * j];
        acc = fma((double)a.x, (double)b.x, acc);
        acc = fma((double)a.y, (double)b.y, acc);
        acc = fma((double)a.z, (double)b.z, acc);
        acc = fma((double)a.w, (double)b.w, acc);
    }
    acc += __shfl_xor(acc, 1);
    acc += __shfl_xor(acc, 2);
    acc += __shfl_xor(acc, 4);
    const double exact = acc + (double)bias[cidx];

    double bv[8]; int bidx[8];
#pragma unroll
    for (int g = 0; g < 8; ++g) { bv[g] = __shfl(exact, g * 8); bidx[g] = __shfl(cidx, g * 8); }

    float fv[4]; int fi[4];
#pragma unroll
    for (int k = 0; k < 4; ++k) {
        double best = -1.0e300; int bi = 1 << 30; int bg = -1;
#pragma unroll
        for (int g = 0; g < 8; ++g) {
            if (bv[g] > best || (bv[g] == best && bidx[g] < bi)) { best = bv[g]; bi = bidx[g]; bg = g; }
        }
#pragma unroll
        for (int g = 0; g < 8; ++g) if (g == bg) bv[g] = -1.0e300;
        fv[k] = (float)best; fi[k] = bi;
    }

    if (lane == 0) {
        const float e1 = expf(fv[1] - fv[0]);
        const float e2 = expf(fv[2] - fv[0]);
        const float e3 = expf(fv[3] - fv[0]);
        const float sm = 1.0f + e1 + e2 + e3;
        float4 ov = {1.0f / sm, e1 / sm, e2 / sm, e3 / sm};
        float4 oi = {(float)fi[0], (float)fi[1], (float)fi[2], (float)fi[3]};
        *(float4*)(&vals[(size_t)tok * 4]) = ov;
        *(float4*)(&inds[(size_t)tok * 4]) = oi;
    }
}

extern "C" void kernel_launch(void* const* d_in, const int* in_sizes, int n_in,
                              void* d_out, int out_size, void* d_ws, size_t ws_size,
                              hipStream_t stream) {
    const float* x    = (const float*)d_in[0];
    const float* w    = (const float*)d_in[1];
    const float* bias = (const float*)d_in[2];

    float* out    = (float*)d_out;
    float* vals   = out;                 // 16384*4
    float* inds   = out + NTOK * 4;      // 16384*4
    float* logits = out + NTOK * 8;      // 16384*128

    // ws layout: whiF | wloF | cand  (~2 MB; no split-K partials)
    short* whiF = (short*)d_ws;
    short* wloF = whiF + (size_t)NEXP * H;
    int*   cand = (int*)(wloF + (size_t)NEXP * H);

    wconv<<<NSTEP, 256, 0, stream>>>(w, whiF, wloF);
    router_gemm_fused<<<NTOK / 32, 256, 0, stream>>>(
        x, whiF, wloF, bias, logits, cand, vals, inds);
    fixup_topk<<<NTOK / 4, 256, 0, stream>>>(x, w, bias, cand, vals, inds);
}